// Round 12
// baseline (123.355 us; speedup 1.0000x reference)
//
#include <hip/hip_runtime.h>
#include <cstdint>

#define E_DIM   1024
#define DH      32
#define M_FEAT  256
#define BT      16384

typedef __attribute__((ext_vector_type(8))) _Float16 f16x8;
typedef __attribute__((ext_vector_type(4))) float f32x4;

// ws layout (shorts=fp16): proj W in MFMA-fragment order, flat = (nt*32 + sub)*512 + lane*8

__device__ __forceinline__ unsigned packh2(_Float16 a, _Float16 b) {
    union { _Float16 h[2]; unsigned u; } t;
    t.h[0] = a; t.h[1] = b;
    return t.u;
}

// x/z 2-term fp16 split: h = fp16_rne(f), l = fp16_rne(f - h)
__device__ __forceinline__ void splitf16_2(float f0, float f1, unsigned& ph, unsigned& pl) {
    _Float16 h0 = (_Float16)f0, h1 = (_Float16)f1;
    float l0 = f0 - (float)h0, l1 = f1 - (float)h1;
    ph = packh2(h0, h1);
    pl = packh2((_Float16)l0, (_Float16)l1);
}

__device__ __forceinline__ void splitf16_8(const float4& a, const float4& b,
                                           uint4& uh, uint4& ul) {
    splitf16_2(a.x, a.y, uh.x, ul.x);
    splitf16_2(a.z, a.w, uh.y, ul.y);
    splitf16_2(b.x, b.y, uh.z, ul.z);
    splitf16_2(b.z, b.w, uh.w, ul.w);
}

// ---------- prep: 64 blocks x 256 thr, direct gather -> fp16 fragment panel ----------
__global__ __launch_bounds__(256) void k_prep(
    const float* __restrict__ Wq, const float* __restrict__ Wk,
    short* __restrict__ ws)
{
    const int gid  = blockIdx.x * 256 + threadIdx.x;   // 0..16383
    const int j0   = (gid & 1) * 4;
    const int lane = (gid >> 1) & 63;
    const int sub  = (gid >> 7) & 31;                  // 32-k subchunk
    const int nt   = gid >> 12;                        // n-tile 0..3
    const int n_g  = nt * 16 + (lane & 15);
    const int k_g  = sub * 32 + (lane >> 4) * 8 + j0;
    const float* __restrict__ src = (n_g < 32) ? Wq : Wk;
    const int col = n_g & 31;
    float f0 = src[(size_t)(k_g + 0) * DH + col];
    float f1 = src[(size_t)(k_g + 1) * DH + col];
    float f2 = src[(size_t)(k_g + 2) * DH + col];
    float f3 = src[(size_t)(k_g + 3) * DH + col];
    uint2 ph;
    ph.x = packh2((_Float16)f0, (_Float16)f1);         // RNE fp16
    ph.y = packh2((_Float16)f2, (_Float16)f3);
    *(uint2*)(ws + (size_t)gid * 4) = ph;
}

// ---------- fused main: TB=16 (4 blocks/CU, 16 waves/CU), BK=256, dist-2 prefetch ----------
#define TB 16
#define XS3 264  // x LDS row stride in shorts (256 data + 8 pad)
#define QS 68    // qk row stride in floats

__global__ __launch_bounds__(256, 4) void k_main(
    const float* __restrict__ x, const float* __restrict__ bq,
    const float* __restrict__ bk, const short* __restrict__ ws,
    const float* __restrict__ w, float* __restrict__ out)
{
    __shared__ __align__(16) short xh_s[2][TB * XS3];   // 2 x 8.4 KB
    __shared__ __align__(16) short xl_s[2][TB * XS3];
    __shared__ __align__(16) float qk_f[TB * QS];

    const int tid  = threadIdx.x;
    const int lane = tid & 63;
    const int wv   = __builtin_amdgcn_readfirstlane(tid >> 6);  // 0..3
    const int ln15 = lane & 15;
    const int g    = lane >> 4;                                  // 0..3
    const long t0  = (long)blockIdx.x * TB;

    const int nrow = wv * 16 + ln15;   // proj output column 0..63 (wave wv owns n-tile wv)
    const float bias = (nrow < 32) ? bq[nrow] : bk[nrow - 32];

    // -------- Phase 1: C[16 tok][64] = x @ [Wq|Wk] (fp16 2-pass), BK=256, dist-2 --------
    const int kq = tid & 15;          // 8-float chunk 0..15 (covers 128 of the 256 k)
    const int mr = tid >> 4;          // token row 0..15

    f32x4 acc0 = {0.f, 0.f, 0.f, 0.f};

    const short* wpB = ws + (size_t)(wv * 32) * 512 + lane * 8;
    const float* xr0 = x + (t0 + mr) * (size_t)E_DIM + kq * 8;

    // two live prefetch sets of a 256-k pair (4 float4); pair k lives in set (k&1)
    float4 s0[4], s1[4];
    {
        float4 t[4];
        t[0] = *(const float4*)(xr0 + 0);   t[1] = *(const float4*)(xr0 + 4);
        t[2] = *(const float4*)(xr0 + 128); t[3] = *(const float4*)(xr0 + 132);
        s1[0] = *(const float4*)(xr0 + 256); s1[1] = *(const float4*)(xr0 + 260);
        s1[2] = *(const float4*)(xr0 + 384); s1[3] = *(const float4*)(xr0 + 388);
        uint4 uh, ul;
        splitf16_8(t[0], t[1], uh, ul);
        *(uint4*)&xh_s[0][mr * XS3 + kq * 8] = uh;
        *(uint4*)&xl_s[0][mr * XS3 + kq * 8] = ul;
        splitf16_8(t[2], t[3], uh, ul);
        *(uint4*)&xh_s[0][mr * XS3 + 128 + kq * 8] = uh;
        *(uint4*)&xl_s[0][mr * XS3 + 128 + kq * 8] = ul;
    }

#pragma unroll
    for (int p = 0; p < 4; ++p) {
        __syncthreads();              // buf (p&1) fully staged; prior reads of it done
        if (p < 2) {                  // issue pair p+2 (slack ~2 full phases)
            float4* d = (p & 1) ? s1 : s0;
            const float* b0 = xr0 + (p + 2) * 256;
            d[0] = *(const float4*)(b0 + 0);   d[1] = *(const float4*)(b0 + 4);
            d[2] = *(const float4*)(b0 + 128); d[3] = *(const float4*)(b0 + 132);
        }
        // B fragments for this phase (8 subtiles), inline from L2-resident panel
        f16x8 bfr[8];
#pragma unroll
        for (int j = 0; j < 8; ++j)
            bfr[j] = *(const f16x8*)(wpB + (size_t)(p * 8 + j) * 512);
#pragma unroll
        for (int j = 0; j < 8; ++j) {
            f16x8 ah0 = *(const f16x8*)&xh_s[p & 1][ln15 * XS3 + j * 32 + g * 8];
            f16x8 al0 = *(const f16x8*)&xl_s[p & 1][ln15 * XS3 + j * 32 + g * 8];
            acc0 = __builtin_amdgcn_mfma_f32_16x16x32_f16(ah0, bfr[j], acc0, 0, 0, 0);
            acc0 = __builtin_amdgcn_mfma_f32_16x16x32_f16(al0, bfr[j], acc0, 0, 0, 0);
        }
        if (p < 3) {                  // stage pair p+1 (issued a full phase ago) into buf (p+1)&1
            const float4* s = ((p + 1) & 1) ? s1 : s0;
            uint4 uh, ul;
            splitf16_8(s[0], s[1], uh, ul);
            *(uint4*)&xh_s[(p + 1) & 1][mr * XS3 + kq * 8] = uh;
            *(uint4*)&xl_s[(p + 1) & 1][mr * XS3 + kq * 8] = ul;
            splitf16_8(s[2], s[3], uh, ul);
            *(uint4*)&xh_s[(p + 1) & 1][mr * XS3 + 128 + kq * 8] = uh;
            *(uint4*)&xl_s[(p + 1) & 1][mr * XS3 + 128 + kq * 8] = ul;
        }
    }

    // issue feature-w fp32 fragment loads; phase-2 writes + barrier cover their latency
    float4 wfa[4], wfb[4];
#pragma unroll
    for (int i = 0; i < 4; ++i) {
        const int nf = (wv * 4 + i) * 16 + ln15;    // feature 0..255
        wfa[i] = *(const float4*)(w + (size_t)nf * DH + g * 8);
        wfb[i] = *(const float4*)(w + (size_t)nf * DH + g * 8 + 4);
    }

    // -------- Phase 2: +bias -> qk LDS (C/D layout: row(tok)=g*4+r, col=ln15) --------
#pragma unroll
    for (int r = 0; r < 4; ++r)
        qk_f[(g * 4 + r) * QS + nrow] = acc0[r] + bias;
    __syncthreads();

    // -------- Phase 4: A = split(q+k) read directly from qk_f; lnA via FMA + shfl --------
    const float LOG2E = 1.4426950408889634f;
    f16x8 a_h, a_l;
    float pwv;
    {
        const int row = ln15;
        float4 qlo = *(const float4*)&qk_f[row * QS + g * 8];
        float4 qhi = *(const float4*)&qk_f[row * QS + g * 8 + 4];
        float4 klo = *(const float4*)&qk_f[row * QS + 32 + g * 8];
        float4 khi = *(const float4*)&qk_f[row * QS + 32 + g * 8 + 4];
        float4 zlo = {qlo.x + klo.x, qlo.y + klo.y, qlo.z + klo.z, qlo.w + klo.w};
        float4 zhi = {qhi.x + khi.x, qhi.y + khi.y, qhi.z + khi.z, qhi.w + khi.w};
        uint4 uh, ul;
        splitf16_8(zlo, zhi, uh, ul);
        a_h = __builtin_bit_cast(f16x8, uh);
        a_l = __builtin_bit_cast(f16x8, ul);
        float pw = qlo.x*qlo.x + qlo.y*qlo.y + qlo.z*qlo.z + qlo.w*qlo.w
                 + qhi.x*qhi.x + qhi.y*qhi.y + qhi.z*qhi.z + qhi.w*qhi.w
                 + klo.x*klo.x + klo.y*klo.y + klo.z*klo.z + klo.w*klo.w
                 + khi.x*khi.x + khi.y*khi.y + khi.z*khi.z + khi.w*khi.w;
        pw += __shfl_xor(pw, 16);
        pw += __shfl_xor(pw, 32);
        pwv = pw;
    }
    float lnAv[4];
#pragma unroll
    for (int r = 0; r < 4; ++r)
        lnAv[r] = -0.5f * LOG2E * __shfl(pwv, g * 4 + r);

    // -------- Phase 4b: S = z @ w^T (fp16 2-pass); wave wv: features wv*64.. --------
    f32x4 facc[4];
#pragma unroll
    for (int i = 0; i < 4; ++i) facc[i] = (f32x4){0.f, 0.f, 0.f, 0.f};

#pragma unroll
    for (int i = 0; i < 4; ++i) {
        uint4 uw;
        uw.x = packh2((_Float16)wfa[i].x, (_Float16)wfa[i].y);
        uw.y = packh2((_Float16)wfa[i].z, (_Float16)wfa[i].w);
        uw.z = packh2((_Float16)wfb[i].x, (_Float16)wfb[i].y);
        uw.w = packh2((_Float16)wfb[i].z, (_Float16)wfb[i].w);
        f16x8 w8 = __builtin_bit_cast(f16x8, uw);
        facc[i] = __builtin_amdgcn_mfma_f32_16x16x32_f16(a_h, w8, facc[i], 0, 0, 0);
        facc[i] = __builtin_amdgcn_mfma_f32_16x16x32_f16(a_l, w8, facc[i], 0, 0, 0);
    }

    // -------- Phase 5: R = 0.5*(exp2(a+s') + exp2(a-s')), prescaled by log2e --------
#pragma unroll
    for (int i = 0; i < 4; ++i) {
        const int n = (wv * 4 + i) * 16 + ln15;
#pragma unroll
        for (int r = 0; r < 4; ++r) {
            float s = facc[i][r] * LOG2E;
            float R = 0.5f * (__builtin_amdgcn_exp2f(lnAv[r] + s)
                            + __builtin_amdgcn_exp2f(lnAv[r] - s));
            __builtin_nontemporal_store(R, &out[(t0 + g * 4 + r) * M_FEAT + n]);
        }
    }
}

extern "C" void kernel_launch(void* const* d_in, const int* in_sizes, int n_in,
                              void* d_out, int out_size, void* d_ws, size_t ws_size,
                              hipStream_t stream) {
    const float* x  = (const float*)d_in[0];
    const float* Wq = (const float*)d_in[1];
    const float* bq = (const float*)d_in[2];
    const float* Wk = (const float*)d_in[3];
    const float* bk = (const float*)d_in[4];
    // d_in[5], d_in[6] = Wv, bv: dead in the reference
    const float* w  = (const float*)d_in[7];
    float* out = (float*)d_out;
    short* ws  = (short*)d_ws;   // 128 KB used (single fp16 weight panel)

    k_prep<<<dim3(64), dim3(256), 0, stream>>>(Wq, Wk, ws);
    k_main<<<dim3(BT / TB), dim3(256), 0, stream>>>(x, bq, bk, ws, w, out);
}

// Round 13
// 117.677 us; speedup vs baseline: 1.0482x; 1.0482x over previous
//
#include <hip/hip_runtime.h>
#include <cstdint>

#define E_DIM   1024
#define DH      32
#define M_FEAT  256
#define BT      16384

typedef __attribute__((ext_vector_type(8))) _Float16 f16x8;
typedef __attribute__((ext_vector_type(4))) float f32x4;

// ws layout (shorts=fp16): proj W in MFMA-fragment order, flat = (nt*32 + sub)*512 + lane*8

__device__ __forceinline__ unsigned packh2(_Float16 a, _Float16 b) {
    union { _Float16 h[2]; unsigned u; } t;
    t.h[0] = a; t.h[1] = b;
    return t.u;
}

// x/z 2-term fp16 split: h = fp16_rne(f), l = fp16_rne(f - h)
__device__ __forceinline__ void splitf16_2(float f0, float f1, unsigned& ph, unsigned& pl) {
    _Float16 h0 = (_Float16)f0, h1 = (_Float16)f1;
    float l0 = f0 - (float)h0, l1 = f1 - (float)h1;
    ph = packh2(h0, h1);
    pl = packh2((_Float16)l0, (_Float16)l1);
}

__device__ __forceinline__ void splitf16_8(const float4& a, const float4& b,
                                           uint4& uh, uint4& ul) {
    splitf16_2(a.x, a.y, uh.x, ul.x);
    splitf16_2(a.z, a.w, uh.y, ul.y);
    splitf16_2(b.x, b.y, uh.z, ul.z);
    splitf16_2(b.z, b.w, uh.w, ul.w);
}

// ---------- prep: 64 blocks x 256 thr, direct gather -> fp16 fragment panel ----------
__global__ __launch_bounds__(256) void k_prep(
    const float* __restrict__ Wq, const float* __restrict__ Wk,
    short* __restrict__ ws)
{
    const int gid  = blockIdx.x * 256 + threadIdx.x;   // 0..16383
    const int j0   = (gid & 1) * 4;
    const int lane = (gid >> 1) & 63;
    const int sub  = (gid >> 7) & 31;                  // 32-k subchunk
    const int nt   = gid >> 12;                        // n-tile 0..3
    const int n_g  = nt * 16 + (lane & 15);
    const int k_g  = sub * 32 + (lane >> 4) * 8 + j0;
    const float* __restrict__ src = (n_g < 32) ? Wq : Wk;
    const int col = n_g & 31;
    float f0 = src[(size_t)(k_g + 0) * DH + col];
    float f1 = src[(size_t)(k_g + 1) * DH + col];
    float f2 = src[(size_t)(k_g + 2) * DH + col];
    float f3 = src[(size_t)(k_g + 3) * DH + col];
    uint2 ph;
    ph.x = packh2((_Float16)f0, (_Float16)f1);         // RNE fp16
    ph.y = packh2((_Float16)f2, (_Float16)f3);
    *(uint2*)(ws + (size_t)gid * 4) = ph;
}

// ---------- fused main: TB=32, fp16 2-pass MFMA; BK=256 (4 phases), dist-2 prefetch ----------
#define TB 32
#define XS3 264  // x LDS row stride in shorts (256 data + 8 pad)
#define QS 68    // qk row stride in floats

__global__ __launch_bounds__(256, 2) void k_main(
    const float* __restrict__ x, const float* __restrict__ bq,
    const float* __restrict__ bk, const short* __restrict__ ws,
    const float* __restrict__ w, float* __restrict__ out)
{
    __shared__ __align__(16) short xh_s[2][TB * XS3];   // 2 x 16.9 KB
    __shared__ __align__(16) short xl_s[2][TB * XS3];
    __shared__ __align__(16) float qk_f[TB * QS];

    const int tid  = threadIdx.x;
    const int lane = tid & 63;
    const int wv   = __builtin_amdgcn_readfirstlane(tid >> 6);  // 0..3
    const int ln15 = lane & 15;
    const int g    = lane >> 4;                                  // 0..3
    const long t0  = (long)blockIdx.x * TB;

    const int nrow = wv * 16 + ln15;   // proj output column 0..63
    const float bias = (nrow < 32) ? bq[nrow] : bk[nrow - 32];

    // -------- Phase 1: C[32 tok][64] = x @ [Wq|Wk] (fp16 2-pass), BK=256, dist-2 --------
    const int kq = tid & 15;          // 8-float chunk 0..15 (covers 128 of the 256 k)
    const int mr = tid >> 4;          // token row 0..15 (also handles mr+16)

    f32x4 acc0 = {0.f, 0.f, 0.f, 0.f};   // tokens 0..15
    f32x4 acc1 = {0.f, 0.f, 0.f, 0.f};   // tokens 16..31

    const short* wpB = ws + (size_t)(wv * 32) * 512 + lane * 8;
    const float* xr0 = x + (t0 + mr) * (size_t)E_DIM + kq * 8;
    const float* xr1 = x + (t0 + mr + 16) * (size_t)E_DIM + kq * 8;

    // two live prefetch sets of a full 256-k pair (8 float4); pair k lives in set (k&1)
    float4 s0[8], s1[8];
    {
        float4 t[8];
        t[0] = *(const float4*)(xr0 + 0);   t[1] = *(const float4*)(xr0 + 4);
        t[2] = *(const float4*)(xr0 + 128); t[3] = *(const float4*)(xr0 + 132);
        t[4] = *(const float4*)(xr1 + 0);   t[5] = *(const float4*)(xr1 + 4);
        t[6] = *(const float4*)(xr1 + 128); t[7] = *(const float4*)(xr1 + 132);
        s1[0] = *(const float4*)(xr0 + 256); s1[1] = *(const float4*)(xr0 + 260);
        s1[2] = *(const float4*)(xr0 + 384); s1[3] = *(const float4*)(xr0 + 388);
        s1[4] = *(const float4*)(xr1 + 256); s1[5] = *(const float4*)(xr1 + 260);
        s1[6] = *(const float4*)(xr1 + 384); s1[7] = *(const float4*)(xr1 + 388);
        uint4 uh, ul;
        splitf16_8(t[0], t[1], uh, ul);
        *(uint4*)&xh_s[0][mr * XS3 + kq * 8] = uh;
        *(uint4*)&xl_s[0][mr * XS3 + kq * 8] = ul;
        splitf16_8(t[2], t[3], uh, ul);
        *(uint4*)&xh_s[0][mr * XS3 + 128 + kq * 8] = uh;
        *(uint4*)&xl_s[0][mr * XS3 + 128 + kq * 8] = ul;
        splitf16_8(t[4], t[5], uh, ul);
        *(uint4*)&xh_s[0][(mr + 16) * XS3 + kq * 8] = uh;
        *(uint4*)&xl_s[0][(mr + 16) * XS3 + kq * 8] = ul;
        splitf16_8(t[6], t[7], uh, ul);
        *(uint4*)&xh_s[0][(mr + 16) * XS3 + 128 + kq * 8] = uh;
        *(uint4*)&xl_s[0][(mr + 16) * XS3 + 128 + kq * 8] = ul;
    }

#pragma unroll
    for (int p = 0; p < 4; ++p) {
        __syncthreads();              // buf (p&1) fully staged; prior reads of it done
        if (p < 2) {                  // issue pair p+2 (slack ~2 full phases)
            float4* d = (p & 1) ? s1 : s0;
            const float* b0 = xr0 + (p + 2) * 256;
            const float* b1 = xr1 + (p + 2) * 256;
            d[0] = *(const float4*)(b0 + 0);   d[1] = *(const float4*)(b0 + 4);
            d[2] = *(const float4*)(b0 + 128); d[3] = *(const float4*)(b0 + 132);
            d[4] = *(const float4*)(b1 + 0);   d[5] = *(const float4*)(b1 + 4);
            d[6] = *(const float4*)(b1 + 128); d[7] = *(const float4*)(b1 + 132);
        }
        // B fragments for this phase (8 subtiles), inline from L2-resident panel
        f16x8 bfr[8];
#pragma unroll
        for (int j = 0; j < 8; ++j)
            bfr[j] = *(const f16x8*)(wpB + (size_t)(p * 8 + j) * 512);
#pragma unroll
        for (int j = 0; j < 8; ++j) {
            f16x8 ah0 = *(const f16x8*)&xh_s[p & 1][ln15 * XS3 + j * 32 + g * 8];
            f16x8 al0 = *(const f16x8*)&xl_s[p & 1][ln15 * XS3 + j * 32 + g * 8];
            f16x8 ah1 = *(const f16x8*)&xh_s[p & 1][(ln15 + 16) * XS3 + j * 32 + g * 8];
            f16x8 al1 = *(const f16x8*)&xl_s[p & 1][(ln15 + 16) * XS3 + j * 32 + g * 8];
            acc0 = __builtin_amdgcn_mfma_f32_16x16x32_f16(ah0, bfr[j], acc0, 0, 0, 0);
            acc0 = __builtin_amdgcn_mfma_f32_16x16x32_f16(al0, bfr[j], acc0, 0, 0, 0);
            acc1 = __builtin_amdgcn_mfma_f32_16x16x32_f16(ah1, bfr[j], acc1, 0, 0, 0);
            acc1 = __builtin_amdgcn_mfma_f32_16x16x32_f16(al1, bfr[j], acc1, 0, 0, 0);
        }
        if (p < 3) {                  // stage pair p+1 (issued a full phase ago) into buf (p+1)&1
            const float4* s = ((p + 1) & 1) ? s1 : s0;
            uint4 uh, ul;
            splitf16_8(s[0], s[1], uh, ul);
            *(uint4*)&xh_s[(p + 1) & 1][mr * XS3 + kq * 8] = uh;
            *(uint4*)&xl_s[(p + 1) & 1][mr * XS3 + kq * 8] = ul;
            splitf16_8(s[2], s[3], uh, ul);
            *(uint4*)&xh_s[(p + 1) & 1][mr * XS3 + 128 + kq * 8] = uh;
            *(uint4*)&xl_s[(p + 1) & 1][mr * XS3 + 128 + kq * 8] = ul;
            splitf16_8(s[4], s[5], uh, ul);
            *(uint4*)&xh_s[(p + 1) & 1][(mr + 16) * XS3 + kq * 8] = uh;
            *(uint4*)&xl_s[(p + 1) & 1][(mr + 16) * XS3 + kq * 8] = ul;
            splitf16_8(s[6], s[7], uh, ul);
            *(uint4*)&xh_s[(p + 1) & 1][(mr + 16) * XS3 + 128 + kq * 8] = uh;
            *(uint4*)&xl_s[(p + 1) & 1][(mr + 16) * XS3 + 128 + kq * 8] = ul;
        }
    }

    // issue feature-w fp32 fragment loads; phase-2 writes + barrier cover their latency
    float4 wfa[4], wfb[4];
#pragma unroll
    for (int i = 0; i < 4; ++i) {
        const int nf = (wv * 4 + i) * 16 + ln15;    // feature 0..255
        wfa[i] = *(const float4*)(w + (size_t)nf * DH + g * 8);
        wfb[i] = *(const float4*)(w + (size_t)nf * DH + g * 8 + 4);
    }

    // -------- Phase 2: +bias -> qk LDS (C/D layout: row(tok)=g*4+r, col=ln15) --------
#pragma unroll
    for (int r = 0; r < 4; ++r) {
        qk_f[(g * 4 + r) * QS + nrow]        = acc0[r] + bias;
        qk_f[(16 + g * 4 + r) * QS + nrow]   = acc1[r] + bias;
    }
    __syncthreads();

    // -------- Phase 4: A = split(q+k) read directly from qk_f; lnA via FMA + shfl --------
    const float LOG2E = 1.4426950408889634f;
    f16x8 a_h[2], a_l[2];
    float pwv[2];
#pragma unroll
    for (int mt = 0; mt < 2; ++mt) {
        const int row = mt * 16 + ln15;
        float4 qlo = *(const float4*)&qk_f[row * QS + g * 8];
        float4 qhi = *(const float4*)&qk_f[row * QS + g * 8 + 4];
        float4 klo = *(const float4*)&qk_f[row * QS + 32 + g * 8];
        float4 khi = *(const float4*)&qk_f[row * QS + 32 + g * 8 + 4];
        float4 zlo = {qlo.x + klo.x, qlo.y + klo.y, qlo.z + klo.z, qlo.w + klo.w};
        float4 zhi = {qhi.x + khi.x, qhi.y + khi.y, qhi.z + khi.z, qhi.w + khi.w};
        uint4 uh, ul;
        splitf16_8(zlo, zhi, uh, ul);
        a_h[mt] = __builtin_bit_cast(f16x8, uh);
        a_l[mt] = __builtin_bit_cast(f16x8, ul);
        float pw = qlo.x*qlo.x + qlo.y*qlo.y + qlo.z*qlo.z + qlo.w*qlo.w
                 + qhi.x*qhi.x + qhi.y*qhi.y + qhi.z*qhi.z + qhi.w*qhi.w
                 + klo.x*klo.x + klo.y*klo.y + klo.z*klo.z + klo.w*klo.w
                 + khi.x*khi.x + khi.y*khi.y + khi.z*khi.z + khi.w*khi.w;
        pw += __shfl_xor(pw, 16);
        pw += __shfl_xor(pw, 32);
        pwv[mt] = pw;
    }
    float lnAv[2][4];
#pragma unroll
    for (int mt = 0; mt < 2; ++mt)
#pragma unroll
        for (int r = 0; r < 4; ++r)
            lnAv[mt][r] = -0.5f * LOG2E * __shfl(pwv[mt], g * 4 + r);

    // -------- Phase 4b: S = z @ w^T (fp16 2-pass); wave wv: features wv*64.. --------
    f32x4 facc[4][2];
#pragma unroll
    for (int i = 0; i < 4; ++i)
#pragma unroll
        for (int mt = 0; mt < 2; ++mt) facc[i][mt] = (f32x4){0.f,0.f,0.f,0.f};

#pragma unroll
    for (int i = 0; i < 4; ++i) {
        uint4 uw;
        uw.x = packh2((_Float16)wfa[i].x, (_Float16)wfa[i].y);
        uw.y = packh2((_Float16)wfa[i].z, (_Float16)wfa[i].w);
        uw.z = packh2((_Float16)wfb[i].x, (_Float16)wfb[i].y);
        uw.w = packh2((_Float16)wfb[i].z, (_Float16)wfb[i].w);
        f16x8 w8 = __builtin_bit_cast(f16x8, uw);
#pragma unroll
        for (int mt = 0; mt < 2; ++mt) {
            facc[i][mt] = __builtin_amdgcn_mfma_f32_16x16x32_f16(a_h[mt], w8, facc[i][mt], 0, 0, 0);
            facc[i][mt] = __builtin_amdgcn_mfma_f32_16x16x32_f16(a_l[mt], w8, facc[i][mt], 0, 0, 0);
        }
    }

    // -------- Phase 5: R = 0.5*(exp2(a+s') + exp2(a-s')), prescaled by log2e --------
#pragma unroll
    for (int i = 0; i < 4; ++i) {
        const int n = (wv * 4 + i) * 16 + ln15;
#pragma unroll
        for (int mt = 0; mt < 2; ++mt) {
#pragma unroll
            for (int r = 0; r < 4; ++r) {
                float s = facc[i][mt][r] * LOG2E;
                float R = 0.5f * (__builtin_amdgcn_exp2f(lnAv[mt][r] + s)
                                + __builtin_amdgcn_exp2f(lnAv[mt][r] - s));
                __builtin_nontemporal_store(R, &out[(t0 + mt * 16 + g * 4 + r) * M_FEAT + n]);
            }
        }
    }
}

extern "C" void kernel_launch(void* const* d_in, const int* in_sizes, int n_in,
                              void* d_out, int out_size, void* d_ws, size_t ws_size,
                              hipStream_t stream) {
    const float* x  = (const float*)d_in[0];
    const float* Wq = (const float*)d_in[1];
    const float* bq = (const float*)d_in[2];
    const float* Wk = (const float*)d_in[3];
    const float* bk = (const float*)d_in[4];
    // d_in[5], d_in[6] = Wv, bv: dead in the reference
    const float* w  = (const float*)d_in[7];
    float* out = (float*)d_out;
    short* ws  = (short*)d_ws;   // 128 KB used (single fp16 weight panel)

    k_prep<<<dim3(64), dim3(256), 0, stream>>>(Wq, Wk, ws);
    k_main<<<dim3(BT / TB), dim3(256), 0, stream>>>(x, bq, bk, ws, w, out);
}